// Round 1
// 819.190 us; speedup vs baseline: 1.3657x; 1.3657x over previous
//
#include <hip/hip_runtime.h>
#include <hip/hip_bf16.h>

// GAT 2-layer, MI355X. fp32 inputs. Split-bf16 MFMA GEMM1 (exact logit path),
// CSR-by-dst aggregation with one wave per destination node.
// R4: replace atomic-scatter CSR build (fill_csr was 285us, 197MB writebacks =
// 15x amplification from cross-XCD partial-line sharing; count_deg + 3 scan
// kernels also removed) with a bucket sort: dst>>8 buckets (256 nodes each),
// LDS histograms + per-block segment reservation -> bucket-contiguous staging
// (lines filled by one block/XCD, single full-line writeback), then one block
// per bucket builds deg/offs/csr entirely in LDS with a 34KB L2-resident
// window. Zero per-edge global atomics. Staging aliases h1f (CSR build runs
// before gemm1).

typedef __attribute__((ext_vector_type(8))) short short8;
typedef __attribute__((ext_vector_type(4))) short short4v;
typedef __attribute__((ext_vector_type(4))) float float4v;

#define NEG_SLOPE 0.2f

static __device__ __forceinline__ short f2bf(float v){
    union { float f; unsigned u; } x; x.f = v;
    unsigned r = x.u + 0x7fffu + ((x.u >> 16) & 1u);   // RNE
    return (short)(r >> 16);
}
static __device__ __forceinline__ float bf2f(short s){
    union { unsigned u; float f; } x; x.u = ((unsigned)(unsigned short)s) << 16;
    return x.f;
}

// ---------- W1 pack: fp32 [512][64] -> bf16 hi/lo, transposed [64][512] ----------
__global__ void pack_w1(const float* __restrict__ W1, short* __restrict__ Whi, short* __restrict__ Wlo){
    int i = blockIdx.x*blockDim.x + threadIdx.x;       // 64*512
    if (i >= 64*512) return;
    int n = i >> 9, k = i & 511;
    float w = W1[k*64 + n];
    short h = f2bf(w);
    Whi[i] = h;
    Wlo[i] = f2bf(w - bf2f(h));
}

// ---------- edge_index int64-layout probe: all odd words zero => int64 ----------
__global__ void detect_i64(const int* __restrict__ ei, int* __restrict__ flag){
    __shared__ int any;
    if (threadIdx.x == 0) any = 0;
    __syncthreads();
    if (ei[2*threadIdx.x + 1] != 0) atomicAdd(&any, 1);
    __syncthreads();
    if (threadIdx.x == 0) flag[0] = (any == 0) ? 1 : 0;   // 1 => int64 layout
}

// ---------- layer-1 GEMM: h1 = x @ W1, split-bf16 MFMA; fp32 + bf16 out ----------
__global__ __launch_bounds__(256) void gemm1(const float* __restrict__ x,
        const short* __restrict__ Whi, const short* __restrict__ Wlo,
        float* __restrict__ h1f, short* __restrict__ h1b, int N){
    int wave = threadIdx.x >> 6, lane = threadIdx.x & 63;
    int m = lane & 15, q = lane >> 4;
    int rowbase = blockIdx.x*64 + wave*16;
    int arow = rowbase + m; if (arow > N-1) arow = N-1;   // clamp; store guarded
    const float4* ap4 = (const float4*)(x + (size_t)arow*512 + q*8);
    float4v acc[4] = {};
    #pragma unroll 4
    for (int kt = 0; kt < 16; ++kt){
        float4 f0 = ap4[kt*8], f1 = ap4[kt*8+1];
        float v[8] = {f0.x,f0.y,f0.z,f0.w,f1.x,f1.y,f1.z,f1.w};
        short8 ahi, alo;
        #pragma unroll
        for (int j = 0; j < 8; ++j){
            union { float f; unsigned u; } t; t.f = v[j];
            ahi[j] = (short)(t.u >> 16);                   // truncation split for hi
            union { unsigned u; float f; } th; th.u = t.u & 0xffff0000u;
            alo[j] = f2bf(v[j] - th.f);
        }
        #pragma unroll
        for (int ct = 0; ct < 4; ++ct){
            const short* wb = Whi + (size_t)(ct*16+m)*512 + kt*32 + q*8;
            const short* wl = Wlo + (size_t)(ct*16+m)*512 + kt*32 + q*8;
            short8 bhi = *(const short8*)wb;
            short8 blo = *(const short8*)wl;
            acc[ct] = __builtin_amdgcn_mfma_f32_16x16x32_bf16(ahi, bhi, acc[ct], 0, 0, 0);
            acc[ct] = __builtin_amdgcn_mfma_f32_16x16x32_bf16(ahi, blo, acc[ct], 0, 0, 0);
            acc[ct] = __builtin_amdgcn_mfma_f32_16x16x32_bf16(alo, bhi, acc[ct], 0, 0, 0);
        }
    }
    #pragma unroll
    for (int ct = 0; ct < 4; ++ct)
        #pragma unroll
        for (int r = 0; r < 4; ++r){
            int row = rowbase + q*4 + r;                   // C/D: col=lane&15, row=quad*4+reg
            if (row < N){
                h1f[(size_t)row*64 + ct*16 + m] = acc[ct][r];
                h1b[(size_t)row*64 + ct*16 + m] = f2bf(acc[ct][r]);
            }
        }
}

// ---------- alpha_s1/alpha_d1: per (n,h) dot over C=8, fp32-exact ----------
__global__ void alpha1(const float* __restrict__ h1f, const float* __restrict__ a_s,
                       const float* __restrict__ a_d, float* __restrict__ as1,
                       float* __restrict__ ad1, int N){
    int t = blockIdx.x*blockDim.x + threadIdx.x;           // t = n*8+h
    if (t >= N*8) return;
    int h = t & 7;
    const float* hp = h1f + (size_t)t*8;
    float s = 0.f, d = 0.f;
    #pragma unroll
    for (int c = 0; c < 8; ++c){
        float v = hp[c];
        s = fmaf(v, a_s[h*8+c], s);
        d = fmaf(v, a_d[h*8+c], d);
    }
    as1[t] = s; ad1[t] = d;
}

// ---------- CSR build via bucket sort (bucket = dst>>8, 256 nodes/bucket) ----------
// Phase A: global per-bucket histogram (LDS-staged, ~K atomics per block).
__global__ __launch_bounds__(256) void bucket_hist(const int* __restrict__ ei,
        const int* __restrict__ flag, int* __restrict__ bhist, int E, int Etot, int K){
    extern __shared__ int hist[];                          // K ints
    for (int i = threadIdx.x; i < K; i += 256) hist[i] = 0;
    __syncthreads();
    int f = flag[0];
    int e0 = blockIdx.x*8192, e1 = min(e0 + 8192, Etot);
    for (int e = e0 + threadIdx.x; e < e1; e += 256){
        int dst = (e < E) ? ei[((size_t)(E + e)) << f] : (e - E);
        atomicAdd(&hist[dst >> 8], 1);
    }
    __syncthreads();
    for (int i = threadIdx.x; i < K; i += 256)
        if (hist[i]) atomicAdd(&bhist[i], hist[i]);
}

// Exclusive scan over K buckets (K < 1024).
__global__ __launch_bounds__(1024) void bucket_scan(const int* __restrict__ bhist,
        int* __restrict__ bbase, int* __restrict__ bcursor, int K){
    __shared__ int s[1024];
    int t = threadIdx.x;
    int v = (t < K) ? bhist[t] : 0;
    s[t] = v; __syncthreads();
    for (int off = 1; off < 1024; off <<= 1){
        int x = (t >= off) ? s[t-off] : 0;
        __syncthreads();
        s[t] += x;
        __syncthreads();
    }
    if (t < K){ int excl = s[t] - v; bbase[t] = excl; bcursor[t] = excl; }
    if (t == K) bbase[K] = s[t];                           // total = Etot
}

// Phase B: scatter edges into bucket-contiguous staging. One reservation atomic
// per (block,bucket); per-edge ranking via LDS atomics. Entry = (src<<8)|dstLow8.
__global__ __launch_bounds__(256) void bucket_place(const int* __restrict__ ei,
        const int* __restrict__ flag, int* __restrict__ bcursor,
        int* __restrict__ staging, int E, int Etot, int K){
    extern __shared__ int sm[];                            // hist[K] + base[K]
    int* hist = sm;
    int* base = sm + K;
    for (int i = threadIdx.x; i < K; i += 256) hist[i] = 0;
    __syncthreads();
    int f = flag[0];
    int e0 = blockIdx.x*8192, e1 = min(e0 + 8192, Etot);
    for (int e = e0 + threadIdx.x; e < e1; e += 256){
        int dst = (e < E) ? ei[((size_t)(E + e)) << f] : (e - E);
        atomicAdd(&hist[dst >> 8], 1);
    }
    __syncthreads();
    for (int i = threadIdx.x; i < K; i += 256){
        int c = hist[i];
        base[i] = c ? atomicAdd(&bcursor[i], c) : 0;
        hist[i] = 0;                                       // reuse as running cursor
    }
    __syncthreads();
    for (int e = e0 + threadIdx.x; e < e1; e += 256){
        int src, dst;
        if (e < E){ src = ei[((size_t)e) << f]; dst = ei[((size_t)(E + e)) << f]; }
        else      { src = dst = e - E; }
        int k = dst >> 8;
        int r = atomicAdd(&hist[k], 1);
        staging[base[k] + r] = (src << 8) | (dst & 255);   // src < 2^24 assumed
    }
}

// Phase C: one block per bucket. Builds deg/offs (replaces count_deg + scans)
// and the final CSR with LDS cursors; all writes land in a ~34KB L2 window.
__global__ __launch_bounds__(256) void bucket_csr(const int* __restrict__ staging,
        const int* __restrict__ bbase, int* __restrict__ offs, int* __restrict__ deg,
        int* __restrict__ csr, int N, int K){
    __shared__ int dcnt[256], sc[256], cur[256];
    int k = blockIdx.x, t = threadIdx.x;
    dcnt[t] = 0;
    __syncthreads();
    int s0 = bbase[k], s1 = bbase[k+1];
    for (int i = s0 + t; i < s1; i += 256)
        atomicAdd(&dcnt[staging[i] & 255], 1);
    __syncthreads();
    int v = dcnt[t];
    sc[t] = v; __syncthreads();
    for (int off = 1; off < 256; off <<= 1){
        int x = (t >= off) ? sc[t-off] : 0;
        __syncthreads();
        sc[t] += x;
        __syncthreads();
    }
    int excl = sc[t] - v;
    int node = (k << 8) + t;
    if (node < N){ offs[node] = s0 + excl; deg[node] = v; }
    cur[t] = excl;
    __syncthreads();
    for (int i = s0 + t; i < s1; i += 256){
        int ent = staging[i];
        int p = atomicAdd(&cur[ent & 255], 1);
        csr[s0 + p] = ent >> 8;
    }
}

// ---------- layer-1 aggregate: wave/dst, 4x pipelined, bf16 gather ----------
__global__ __launch_bounds__(256) void agg1(const short* __restrict__ h1b,
        const float* __restrict__ as1, const float* __restrict__ ad1,
        const int* __restrict__ offs, const int* __restrict__ deg, const int* __restrict__ csr,
        const float* __restrict__ b1, short* __restrict__ x1b, int N){
    int w = blockIdx.x*4 + (threadIdx.x >> 6);
    if (w >= N) return;
    int lane = threadIdx.x & 63, h = lane >> 3;
    int s0 = offs[w], d = deg[w];
    float ad = ad1[w*8 + h];
    float l = 0.f, acc = 0.f;
    int i = 0;
    for (; i + 4 <= d; i += 4){
        int sa = csr[s0+i], sb = csr[s0+i+1], sc = csr[s0+i+2], sd = csr[s0+i+3];
        float ea = as1[sa*8+h], eb = as1[sb*8+h], ec = as1[sc*8+h], ed = as1[sd*8+h];
        float va = bf2f(h1b[(size_t)sa*64 + lane]);
        float vb = bf2f(h1b[(size_t)sb*64 + lane]);
        float vc = bf2f(h1b[(size_t)sc*64 + lane]);
        float vd = bf2f(h1b[(size_t)sd*64 + lane]);
        ea += ad; ea = (ea > 0.f) ? ea : NEG_SLOPE*ea; float pa = __expf(ea);
        eb += ad; eb = (eb > 0.f) ? eb : NEG_SLOPE*eb; float pb = __expf(eb);
        ec += ad; ec = (ec > 0.f) ? ec : NEG_SLOPE*ec; float pc = __expf(ec);
        ed += ad; ed = (ed > 0.f) ? ed : NEG_SLOPE*ed; float pd = __expf(ed);
        l += (pa + pb) + (pc + pd);
        acc = fmaf(pa, va, acc); acc = fmaf(pb, vb, acc);
        acc = fmaf(pc, vc, acc); acc = fmaf(pd, vd, acc);
    }
    for (; i < d; ++i){
        int s = csr[s0 + i];
        float e = as1[s*8 + h] + ad;
        e = (e > 0.f) ? e : NEG_SLOPE*e;
        float p = __expf(e);
        l += p;
        acc = fmaf(p, bf2f(h1b[(size_t)s*64 + lane]), acc);
    }
    float o = acc/(l + 1e-16f) + b1[lane];
    o = (o > 0.f) ? o : (__expf(o) - 1.f);                  // ELU
    x1b[(size_t)w*64 + lane] = f2bf(o);
}

// ---------- layer-2 GEMM fused with alpha2: wave/node; fp32 logit path ----------
__global__ __launch_bounds__(256) void gemm2a(const short* __restrict__ x1b,
        const float* __restrict__ W2, const float* __restrict__ aS2, const float* __restrict__ aD2,
        short* __restrict__ h2b, float* __restrict__ as2, float* __restrict__ ad2, int N){
    __shared__ float w2s[64*40];                            // 10,240 B
    __shared__ float xs[4][64];
    int tid = threadIdx.x;
    for (int i = tid; i < 64*40; i += 256) w2s[i] = W2[i];  // W2 [64][40] row-major
    int wv = tid >> 6, lane = tid & 63;
    int n = blockIdx.x*4 + wv;
    bool valid = n < N;
    if (valid && lane < 16){
        short4v xv = *(const short4v*)&x1b[(size_t)n*64 + lane*4];
        xs[wv][lane*4+0] = bf2f(xv[0]);
        xs[wv][lane*4+1] = bf2f(xv[1]);
        xs[wv][lane*4+2] = bf2f(xv[2]);
        xs[wv][lane*4+3] = bf2f(xv[3]);
    }
    __syncthreads();
    int c = (lane < 40) ? lane : 39;
    float acc = 0.f;
    #pragma unroll 8
    for (int k = 0; k < 64; ++k)
        acc = fmaf(xs[wv][k], w2s[k*40 + c], acc);
    float s = (lane < 40) ? acc * aS2[lane] : 0.f;
    float d = (lane < 40) ? acc * aD2[lane] : 0.f;
    #pragma unroll
    for (int off = 32; off > 0; off >>= 1){ s += __shfl_down(s, off, 64); d += __shfl_down(d, off, 64); }
    if (valid){
        if (lane < 40) h2b[(size_t)n*40 + lane] = f2bf(acc);
        if (lane == 0){ as2[n] = s; ad2[n] = d; }
    }
}

// ---------- layer-2 aggregate: wave/dst, 4x pipelined, bf16 gather ----------
__global__ __launch_bounds__(256) void agg2(const short* __restrict__ h2b,
        const float* __restrict__ as2, const float* __restrict__ ad2,
        const int* __restrict__ offs, const int* __restrict__ deg, const int* __restrict__ csr,
        const float* __restrict__ b2, float* __restrict__ out, int N){
    int w = blockIdx.x*4 + (threadIdx.x >> 6);
    if (w >= N) return;
    int lane = threadIdx.x & 63;
    int c = (lane < 40) ? lane : 0;                          // clamp: in-bounds loads
    int s0 = offs[w], d = deg[w];
    float ad = ad2[w];
    float l = 0.f, acc = 0.f;
    int i = 0;
    for (; i + 4 <= d; i += 4){
        int sa = csr[s0+i], sb = csr[s0+i+1], sc = csr[s0+i+2], sd = csr[s0+i+3];
        float ea = as2[sa], eb = as2[sb], ec = as2[sc], ed = as2[sd];
        float va = bf2f(h2b[(size_t)sa*40 + c]);
        float vb = bf2f(h2b[(size_t)sb*40 + c]);
        float vc = bf2f(h2b[(size_t)sc*40 + c]);
        float vd = bf2f(h2b[(size_t)sd*40 + c]);
        ea += ad; ea = (ea > 0.f) ? ea : NEG_SLOPE*ea; float pa = __expf(ea);
        eb += ad; eb = (eb > 0.f) ? eb : NEG_SLOPE*eb; float pb = __expf(eb);
        ec += ad; ec = (ec > 0.f) ? ec : NEG_SLOPE*ec; float pc = __expf(ec);
        ed += ad; ed = (ed > 0.f) ? ed : NEG_SLOPE*ed; float pd = __expf(ed);
        l += (pa + pb) + (pc + pd);
        acc = fmaf(pa, va, acc); acc = fmaf(pb, vb, acc);
        acc = fmaf(pc, vc, acc); acc = fmaf(pd, vd, acc);
    }
    for (; i < d; ++i){
        int s = csr[s0 + i];
        float e = as2[s] + ad;
        e = (e > 0.f) ? e : NEG_SLOPE*e;
        float p = __expf(e);
        l += p;
        acc = fmaf(p, bf2f(h2b[(size_t)s*40 + c]), acc);
    }
    if (lane < 40) out[(size_t)w*40 + lane] = acc/(l + 1e-16f) + b2[lane];
}

extern "C" void kernel_launch(void* const* d_in, const int* in_sizes, int n_in,
                              void* d_out, int out_size, void* d_ws, size_t ws_size,
                              hipStream_t stream) {
    const float* x    = (const float*)d_in[0];
    const int*   ei   = (const int*)d_in[1];
    const float* W1   = (const float*)d_in[2];
    const float* aS1  = (const float*)d_in[3];
    const float* aD1  = (const float*)d_in[4];
    const float* b1   = (const float*)d_in[5];
    const float* W2   = (const float*)d_in[6];
    const float* aS2  = (const float*)d_in[7];
    const float* aD2  = (const float*)d_in[8];
    const float* b2   = (const float*)d_in[9];
    float* out = (float*)d_out;

    const int N    = in_sizes[0] / 512;
    const int E    = in_sizes[1] / 2;
    const int Etot = E + N;
    const int K    = (N + 255) >> 8;          // buckets of 256 dst nodes
    const int nAB  = (Etot + 8191) / 8192;    // edge chunks for hist/place

    // workspace carve (256B aligned)
    char* p = (char*)d_ws;
    auto carve = [&](size_t bytes)->char*{ char* q = p; p += ((bytes + 255) & ~(size_t)255); return q; };
    float* h1f   = (float*)carve((size_t)N*64*4);
    short* h1b   = (short*)carve((size_t)N*64*2);
    short* x1b   = (short*)carve((size_t)N*64*2);
    short* h2b   = (short*)carve((size_t)N*40*2);
    float* as1   = (float*)carve((size_t)N*8*4);
    float* ad1   = (float*)carve((size_t)N*8*4);
    float* as2   = (float*)carve((size_t)N*4);
    float* ad2   = (float*)carve((size_t)N*4);
    int*   deg   = (int*)carve((size_t)N*4);
    int*   offs  = (int*)carve((size_t)N*4);
    int*   bhist = (int*)carve((size_t)(K+1)*4);
    int*   bbase = (int*)carve((size_t)(K+1)*4);
    int*   bcursor=(int*)carve((size_t)(K+1)*4);
    int*   flag  = (int*)carve(256);
    short* Whi   = (short*)carve(64*512*2);
    short* Wlo   = (short*)carve(64*512*2);
    int*   csr   = (int*)carve((size_t)Etot*4);
    // staging (Etot*4 = 13.2MB) aliases h1f (25.6MB): CSR build completes
    // before gemm1 writes h1f, single stream preserves the ordering.
    int*   staging = (int*)h1f;

    hipMemsetAsync(bhist, 0, (size_t)K*4, stream);

    detect_i64<<<1, 1024, 0, stream>>>(ei, flag);
    pack_w1<<<(64*512 + 255)/256, 256, 0, stream>>>(W1, Whi, Wlo);

    // CSR build: bucket sort, no per-edge global atomics, no random scatter.
    bucket_hist <<<nAB, 256, (size_t)K*4,   stream>>>(ei, flag, bhist, E, Etot, K);
    bucket_scan <<<1, 1024, 0,              stream>>>(bhist, bbase, bcursor, K);
    bucket_place<<<nAB, 256, (size_t)2*K*4, stream>>>(ei, flag, bcursor, staging, E, Etot, K);
    bucket_csr  <<<K, 256, 0,               stream>>>(staging, bbase, offs, deg, csr, N, K);

    gemm1 <<<(N + 63)/64,    256, 0, stream>>>(x, Whi, Wlo, h1f, h1b, N);
    alpha1<<<(N*8 + 255)/256, 256, 0, stream>>>(h1f, aS1, aD1, as1, ad1, N);

    agg1  <<<(N + 3)/4,  256, 0, stream>>>(h1b, as1, ad1, offs, deg, csr, b1, x1b, N);
    gemm2a<<<(N + 3)/4,  256, 0, stream>>>(x1b, W2, aS2, aD2, h2b, as2, ad2, N);
    agg2  <<<(N + 3)/4,  256, 0, stream>>>(h2b, as2, ad2, offs, deg, csr, b2, out, N);
}